// Round 14
// baseline (27.093 us; speedup 1.0000x reference)
//
#include <hip/hip_runtime.h>
#include <hip/hip_bf16.h>

// Problem constants (match reference)
#define NN 1024
#define FF 256
#define DD 64
#define RR 11
#define EE 2048
#define ALPHA 0.2f
#define TPB 512
#define EPT (EE / TPB)          // 4 edges per thread in K1
#define PERM_CAP 2176           // >= 2048 + 11*7 padding
#define K2_GRID (PERM_CAP / 8)  // 272 tiles (ntiles <= 267)

// ws layout (bytes):
//   0     : int ntiles
//   256   : int perm[PERM_CAP]   (8704 B)
//   12288 : float inv[FF]        (1 KB)   1/sum_e exp(v[e,f])
//   16384 : float pT[RR*FF]      (11 KB)  r-major: pT[r*FF+f]
//   32768 : float qT[RR*FF]      (11 KB)
// NO cbuf: K2 recomputes c = exp(v)*inv[f]*xd on the fly. Only ~24 KB of
// clean table state crosses the kernel boundary (vs 2 MB cross-XCD dirty
// cbuf lines before).

// K1: blocks 0..255 = feature f (XCD-grouped swizzle). Direct x gathers
//     (single pass -> LDS staging is pure overhead), p/q wave-dots, score
//     pass accumulating s = sum(exp(v)) only. Block 256: relation sort.
__global__ __launch_bounds__(TPB) void k1_stats(
    const float* __restrict__ x, const float* __restrict__ W,
    const float* __restrict__ a, const int* __restrict__ src,
    const int* __restrict__ dst, const int* __restrict__ rel,
    float* __restrict__ pT, float* __restrict__ qT,
    float* __restrict__ inv, int* __restrict__ perm,
    int* __restrict__ ntiles_p) {

    const int b    = blockIdx.x;   // 0..256
    const int tid  = threadIdx.x;  // 0..511
    const int wid  = tid >> 6;     // 0..7
    const int lane = tid & 63;

    __shared__ float p_sh[RR], q_sh[RR];
    __shared__ float red_s[8];
    __shared__ int   hist[16], off_sh[16];

    if (b == FF) {
        // dedicated sort block (runs concurrently with feature blocks)
        if (tid < 16) hist[tid] = 0;
        __syncthreads();
        for (int e = tid; e < EE; e += TPB) atomicAdd(&hist[rel[e]], 1);
        __syncthreads();
        if (tid == 0) {
            int acc = 0;
            for (int r = 0; r < RR; ++r) {
                off_sh[r] = acc;
                acc += (hist[r] + 7) & ~7;
            }
            *ntiles_p = acc >> 3;      // tiles of 8 edges
        }
        __syncthreads();
        for (int i = tid; i < PERM_CAP; i += TPB) perm[i] = -1;
        __syncthreads();
        for (int e = tid; e < EE; e += TPB) {
            int pos = atomicAdd(&off_sh[rel[e]], 1);
            perm[pos] = e;
        }
        return;
    }

    const int f = ((b & 7) << 5) | (b >> 3);   // XCD-grouped feature

    // p/q: p[r]=dot(W[r,f,:],a[:64]), q[r]=dot(W[r,f,:],a[64:]); store r-major
    for (int r = wid; r < RR; r += 8) {
        float w  = W[((size_t)r * FF + f) * DD + lane];
        float pa = w * a[lane];
        float qa = w * a[DD + lane];
        #pragma unroll
        for (int o = 32; o > 0; o >>= 1) {
            pa += __shfl_down(pa, o);
            qa += __shfl_down(qa, o);
        }
        if (lane == 0) {
            p_sh[r] = pa; q_sh[r] = qa;
            pT[r * FF + f] = pa;
            qT[r * FF + f] = qa;
        }
    }
    __syncthreads();

    // single pass over edges: s = sum(exp(lrelu(v))); batched direct gathers
    int siA[EPT], diA[EPT], rA[EPT];
    #pragma unroll
    for (int k = 0; k < EPT; ++k) {
        int e = tid + k * TPB;
        siA[k] = src[e]; diA[k] = dst[e]; rA[k] = rel[e];
    }
    float xsA[EPT], xdA[EPT];
    #pragma unroll
    for (int k = 0; k < EPT; ++k) {        // 8 independent gathers in flight
        xsA[k] = x[(size_t)siA[k] * FF + f];
        xdA[k] = x[(size_t)diA[k] * FF + f];
    }
    float s = 0.0f;
    #pragma unroll
    for (int k = 0; k < EPT; ++k) {
        float v = xsA[k] * p_sh[rA[k]] + xdA[k] * q_sh[rA[k]];
        v = v > 0.0f ? v : ALPHA * v;
        s += expf(v);                      // |v| <~ 2, no max needed (R12-proven)
    }
    #pragma unroll
    for (int o = 32; o > 0; o >>= 1) s += __shfl_down(s, o);
    if (lane == 0) red_s[wid] = s;
    __syncthreads();
    float st = red_s[0];
    #pragma unroll
    for (int i = 1; i < 8; ++i) st += red_s[i];
    if (tid == 0) inv[f] = 1.0f / st;
}

// K2: block = tile of 8 same-relation edges (XCD-swizzled tile id; one wave
//     per edge, lane = d-quad layout). Stages 3 KB of tables (p_r, q_r, inv)
//     + streams W_r through LDS in double-buffered 8 KB chunks. Recomputes
//     c = exp(v)*inv[f]*xd from 16B-broadcast x loads -- no cbuf.
__global__ __launch_bounds__(TPB) void k2_out(
    const float* __restrict__ x, const float* __restrict__ W,
    const int* __restrict__ src, const int* __restrict__ dst,
    const int* __restrict__ rel,
    const float* __restrict__ pT, const float* __restrict__ qT,
    const float* __restrict__ inv, const int* __restrict__ perm,
    const int* __restrict__ ntiles_p, float* __restrict__ out) {

    const int b = blockIdx.x;                  // 0..271
    const int t = (b & 7) * 34 + (b >> 3);     // bijective 0..271, XCD-grouped
    if (t >= *ntiles_p) return;                // block-uniform

    const int tid  = threadIdx.x;
    const int wid  = tid >> 6;
    const int lane = tid & 63;

    __shared__ float Wl[32 * DD];  // 8 KB chunk: W_r[fc*32 .. +32][:]
    __shared__ float p_l[FF], q_l[FF], iv_l[FF];   // 3 KB tables
    __shared__ int   e_sh[8];

    if (tid < 8) e_sh[tid] = perm[t * 8 + tid];
    __syncthreads();

    const int r = rel[e_sh[0]];    // first slot of a tile is always valid
    const size_t rb = (size_t)r * FF;
    if (tid < FF) { p_l[tid] = pT[rb + tid]; iv_l[tid] = inv[tid]; }
    else          { q_l[tid - FF] = qT[rb + tid - FF]; }

    const int e = e_sh[wid];
    const int es = (e >= 0) ? e : 0;
    const float* __restrict__ xrs = x + (size_t)src[es] * FF;
    const float* __restrict__ xrd = x + (size_t)dst[es] * FF;
    const float* __restrict__ Wr  = W + rb * DD;

    const int fg = lane >> 4;      // 0..3: f within a 4-group
    const int dq = lane & 15;      // 0..15: d-quad
    const int srow = tid >> 4;     // 0..31: staging row
    const int scol = tid & 15;     // 0..15: staging float4 col

    // prefetch chunk 0
    float4 nxt = *(const float4*)&Wr[(size_t)srow * DD + scol * 4];

    float4 acc = make_float4(0.f, 0.f, 0.f, 0.f);
    #pragma unroll
    for (int fc = 0; fc < FF / 32; ++fc) {   // 8 chunks of 32 features
        __syncthreads();                     // tables staged / Wl reusable
        *(float4*)&Wl[srow * DD + scol * 4] = nxt;
        __syncthreads();
        if (fc < FF / 32 - 1)                // next chunk load overlaps FMAs
            nxt = *(const float4*)
                &Wr[(size_t)((fc + 1) * 32 + srow) * DD + scol * 4];
        if (e >= 0) {
            #pragma unroll
            for (int j = 0; j < 8; ++j) {
                int lf = j * 4 + fg;                    // local f 0..31
                int gf = fc * 32 + lf;                  // global f
                float xs = xrs[gf];                     // 16B/wave broadcast
                float xd = xrd[gf];
                float v = xs * p_l[gf] + xd * q_l[gf];
                v = v > 0.0f ? v : ALPHA * v;
                float c = expf(v) * iv_l[gf] * xd;      // attn * x[dst,f]
                float4 w4 = *(const float4*)&Wl[lf * DD + dq * 4];
                acc.x = fmaf(c, w4.x, acc.x);
                acc.y = fmaf(c, w4.y, acc.y);
                acc.z = fmaf(c, w4.z, acc.z);
                acc.w = fmaf(c, w4.w, acc.w);
            }
        }
    }

    // sum the 4 f-groups: lanes (l, l^16, l^32, l^48) hold same d-quad
    #pragma unroll
    for (int o = 16; o <= 32; o <<= 1) {
        acc.x += __shfl_xor(acc.x, o);
        acc.y += __shfl_xor(acc.y, o);
        acc.z += __shfl_xor(acc.z, o);
        acc.w += __shfl_xor(acc.w, o);
    }
    if (e >= 0 && fg == 0)
        *(float4*)&out[(size_t)e * DD + dq * 4] = acc;
}

extern "C" void kernel_launch(void* const* d_in, const int* in_sizes, int n_in,
                              void* d_out, int out_size, void* d_ws, size_t ws_size,
                              hipStream_t stream) {
    const float* x  = (const float*)d_in[0];   // [N, F]
    const float* W  = (const float*)d_in[1];   // [R, F, D]
    const float* a  = (const float*)d_in[2];   // [2*D]
    const int* src  = (const int*)d_in[3];     // [E]
    const int* dst  = (const int*)d_in[4];     // [E]
    const int* rel  = (const int*)d_in[5];     // [E]
    float* out      = (float*)d_out;           // [E*D]

    char* wsb = (char*)d_ws;
    int*   ntiles_p = (int*)wsb;
    int*   perm     = (int*)(wsb + 256);
    float* inv      = (float*)(wsb + 12288);
    float* pT       = (float*)(wsb + 16384);
    float* qT       = (float*)(wsb + 32768);

    k1_stats<<<FF + 1, TPB, 0, stream>>>(x, W, a, src, dst, rel,
                                         pT, qT, inv, perm, ntiles_p);
    k2_out<<<K2_GRID, TPB, 0, stream>>>(x, W, src, dst, rel, pT, qT, inv,
                                        perm, ntiles_p, out);
}

// Round 15
// 21.680 us; speedup vs baseline: 1.2497x; 1.2497x over previous
//
#include <hip/hip_runtime.h>
#include <hip/hip_bf16.h>

// Problem constants (match reference)
#define NN 1024
#define FF 256
#define DD 64
#define RR 11
#define EE 2048
#define ALPHA 0.2f
#define TPB 512
#define EPT (EE / TPB)          // 4 edges per thread in K1
#define TILE_E 32               // edges per K2 tile (same relation)
#define PERM_CAP 2432           // >= 2048 + 11*31, = 76*32
#define K2_GRID (PERM_CAP / TILE_E)  // 76

// ws layout (bytes):
//   0     : int ntiles
//   256   : int perm[PERM_CAP]   (9728 B)
//   16384 : float cbuf[EE*FF]    (2 MB, e-major: cbuf[e*FF+f])
// cbuf round-trip proven CHEAPER than K2 recompute (R12 21.5 vs R14 27.1).

// K1 (R12-proven): block b owns feature f=(b&7)*32+(b>>3) [XCD-grouped].
//     Stage x[:,f] in LDS; p/q wave-dots; single-pass softmax (no max pass,
//     |v|<~2); write c[e,f]=exp(v)*xd/sum (e-major). Block 0 also sorts
//     edges by relation into 32-padded buckets.
__global__ __launch_bounds__(TPB) void k1_coef(
    const float* __restrict__ x, const float* __restrict__ W,
    const float* __restrict__ a, const int* __restrict__ src,
    const int* __restrict__ dst, const int* __restrict__ rel,
    float* __restrict__ cbuf, int* __restrict__ perm,
    int* __restrict__ ntiles_p) {

    const int b    = blockIdx.x;                 // 0..255
    const int f    = ((b & 7) << 5) | (b >> 3);  // XCD-grouped feature
    const int tid  = threadIdx.x;                // 0..511
    const int wid  = tid >> 6;                   // 0..7
    const int lane = tid & 63;

    __shared__ float xcol[NN];     // 4 KB: x[:, f]
    __shared__ float p_sh[RR], q_sh[RR];
    __shared__ float red_s[8];
    __shared__ int   hist[16], off_sh[16];

    // stage column f of x (lines L2-shared within this XCD)
    for (int i = tid; i < NN; i += TPB) xcol[i] = x[(size_t)i * FF + f];

    // own-feature p/q: p[r]=dot(W[r,f,:],a[:64]), q[r]=dot(W[r,f,:],a[64:])
    for (int r = wid; r < RR; r += 8) {
        float w  = W[((size_t)r * FF + f) * DD + lane];
        float pa = w * a[lane];
        float qa = w * a[DD + lane];
        #pragma unroll
        for (int o = 32; o > 0; o >>= 1) {
            pa += __shfl_down(pa, o);
            qa += __shfl_down(qa, o);
        }
        if (lane == 0) { p_sh[r] = pa; q_sh[r] = qa; }
    }
    __syncthreads();   // xcol + p_sh/q_sh ready

    // single pass: u = exp(v)*xd, s = sum(exp(v))
    float uvals[EPT];
    float s = 0.0f;
    #pragma unroll
    for (int k = 0; k < EPT; ++k) {
        int e = tid + k * TPB;
        float xs = xcol[src[e]];
        float xd = xcol[dst[e]];
        int r = rel[e];
        float v = xs * p_sh[r] + xd * q_sh[r];
        v = v > 0.0f ? v : ALPHA * v;
        float ev = expf(v);
        uvals[k] = ev * xd;
        s += ev;
    }
    #pragma unroll
    for (int o = 32; o > 0; o >>= 1) s += __shfl_down(s, o);
    if (lane == 0) red_s[wid] = s;
    __syncthreads();
    float st = red_s[0];
    #pragma unroll
    for (int i = 1; i < 8; ++i) st += red_s[i];
    float inv = 1.0f / st;

    // fused coefficient c[e,f] = attn[e,f]*x[dst,f], e-major
    #pragma unroll
    for (int k = 0; k < EPT; ++k) {
        int e = tid + k * TPB;
        cbuf[(size_t)e * FF + f] = uvals[k] * inv;
    }

    // block 0 (f==0): counting sort by relation, buckets padded to 32
    if (b == 0) {
        if (tid < 16) hist[tid] = 0;
        __syncthreads();
        for (int e = tid; e < EE; e += TPB) atomicAdd(&hist[rel[e]], 1);
        __syncthreads();
        if (tid == 0) {
            int acc = 0;
            for (int r = 0; r < RR; ++r) {
                off_sh[r] = acc;
                acc += (hist[r] + TILE_E - 1) & ~(TILE_E - 1);
            }
            *ntiles_p = acc / TILE_E;
        }
        __syncthreads();
        for (int i = tid; i < PERM_CAP; i += TPB) perm[i] = -1;
        __syncthreads();
        for (int e = tid; e < EE; e += TPB) {
            int pos = atomicAdd(&off_sh[rel[e]], 1);
            perm[pos] = e;
        }
    }
}

// K2: block = tile of 32 same-relation edges; 8 waves, wave = 4 edges.
//     W_r streamed through LDS in double-buffered 8 KB chunks, amortized
//     over 32 edges (4x fewer barrier/stage rounds per edge than R12).
//     Per chunk per lane: 8 LDS b128 W loads + 32 broadcast c loads + 128 FMA.
__global__ __launch_bounds__(TPB) void k2_out(
    const float* __restrict__ W, const int* __restrict__ rel,
    const float* __restrict__ cbuf, const int* __restrict__ perm,
    const int* __restrict__ ntiles_p, float* __restrict__ out) {

    const int t = blockIdx.x;      // 0..75
    if (t >= *ntiles_p) return;    // block-uniform

    const int tid  = threadIdx.x;
    const int wid  = tid >> 6;
    const int lane = tid & 63;

    __shared__ float Wl[32 * DD];  // 8 KB chunk: W_r[fc*32 .. +32][:]
    __shared__ int   e_sh[TILE_E];

    if (tid < TILE_E) e_sh[tid] = perm[t * TILE_E + tid];
    __syncthreads();

    // buckets are 32-aligned; pads only at a bucket's tail -> slot 0 valid
    const int r = rel[e_sh[0]];
    const float* __restrict__ Wr = W + (size_t)r * FF * DD;

    int eb[4];
    const float* ce[4];
    float4 acc[4];
    #pragma unroll
    for (int j = 0; j < 4; ++j) {
        eb[j]  = e_sh[wid * 4 + j];
        ce[j]  = cbuf + (size_t)(eb[j] >= 0 ? eb[j] : 0) * FF;
        acc[j] = make_float4(0.f, 0.f, 0.f, 0.f);
    }

    const int fg = lane >> 4;      // 0..3: f within a 4-group
    const int dq = lane & 15;      // 0..15: d-quad
    const int srow = tid >> 4;     // 0..31: staging row
    const int scol = tid & 15;     // 0..15: staging float4 col

    // prefetch chunk 0
    float4 nxt = *(const float4*)&Wr[(size_t)srow * DD + scol * 4];

    #pragma unroll
    for (int fc = 0; fc < FF / 32; ++fc) {   // 8 chunks of 32 features
        __syncthreads();                     // Wl free
        *(float4*)&Wl[srow * DD + scol * 4] = nxt;
        __syncthreads();
        if (fc < FF / 32 - 1)                // next chunk overlaps the FMAs
            nxt = *(const float4*)
                &Wr[(size_t)((fc + 1) * 32 + srow) * DD + scol * 4];
        #pragma unroll
        for (int i = 0; i < 8; ++i) {
            int lf = i * 4 + fg;                        // local f 0..31
            float4 w4 = *(const float4*)&Wl[lf * DD + dq * 4];
            int gf = fc * 32 + lf;
            #pragma unroll
            for (int j = 0; j < 4; ++j) {
                float c = ce[j][gf];                    // broadcast/16 lanes
                acc[j].x = fmaf(c, w4.x, acc[j].x);
                acc[j].y = fmaf(c, w4.y, acc[j].y);
                acc[j].z = fmaf(c, w4.z, acc[j].z);
                acc[j].w = fmaf(c, w4.w, acc[j].w);
            }
        }
    }

    // per edge: sum the 4 f-groups (lanes l, l^16, l^32, l^48 share d-quad)
    #pragma unroll
    for (int j = 0; j < 4; ++j) {
        #pragma unroll
        for (int o = 16; o <= 32; o <<= 1) {
            acc[j].x += __shfl_xor(acc[j].x, o);
            acc[j].y += __shfl_xor(acc[j].y, o);
            acc[j].z += __shfl_xor(acc[j].z, o);
            acc[j].w += __shfl_xor(acc[j].w, o);
        }
        if (eb[j] >= 0 && fg == 0)
            *(float4*)&out[(size_t)eb[j] * DD + dq * 4] = acc[j];
    }
}

extern "C" void kernel_launch(void* const* d_in, const int* in_sizes, int n_in,
                              void* d_out, int out_size, void* d_ws, size_t ws_size,
                              hipStream_t stream) {
    const float* x  = (const float*)d_in[0];   // [N, F]
    const float* W  = (const float*)d_in[1];   // [R, F, D]
    const float* a  = (const float*)d_in[2];   // [2*D]
    const int* src  = (const int*)d_in[3];     // [E]
    const int* dst  = (const int*)d_in[4];     // [E]
    const int* rel  = (const int*)d_in[5];     // [E]
    float* out      = (float*)d_out;           // [E*D]

    char* wsb = (char*)d_ws;
    int*   ntiles_p = (int*)wsb;
    int*   perm     = (int*)(wsb + 256);
    float* cbuf     = (float*)(wsb + 16384);

    k1_coef<<<FF, TPB, 0, stream>>>(x, W, a, src, dst, rel,
                                    cbuf, perm, ntiles_p);
    k2_out<<<K2_GRID, TPB, 0, stream>>>(W, rel, cbuf, perm, ntiles_p, out);
}